// Round 1
// baseline (337.158 us; speedup 1.0000x reference)
//
#include <hip/hip_runtime.h>
#include <hip/hip_bf16.h>
#include <stdint.h>

// Problem constants (B=2, T=2048, D=1024, H=16, DK=64)
#define Bc   2
#define Tc   2048
#define Dc   1024
#define Hc   16
#define DKc  64
#define BTc  4096
#define LOG2E 1.44269504088896f

typedef unsigned short u16;
typedef __attribute__((ext_vector_type(8))) short bf16x8;
typedef __attribute__((ext_vector_type(4))) float f32x4;

static __device__ __forceinline__ u16 f2bf(float f) {
  union { float f; unsigned u; } v; v.f = f;
  unsigned r = v.u + 0x7fffu + ((v.u >> 16) & 1u);   // RNE
  return (u16)(r >> 16);
}

static __device__ __forceinline__ f32x4 mfma16(bf16x8 a, bf16x8 b, f32x4 c) {
  return __builtin_amdgcn_mfma_f32_16x16x32_bf16(a, b, c, 0, 0, 0);
}

// ---------------- f32 -> bf16 conversion (grid.z selects tensor) -------------
__global__ void conv_kernel(const float* __restrict__ a0, const float* __restrict__ a1,
                            const float* __restrict__ a2, const float* __restrict__ a3,
                            u16* __restrict__ o0, u16* __restrict__ o1,
                            u16* __restrict__ o2, u16* __restrict__ o3, int n4) {
  int z = blockIdx.z;
  const float* a = z == 0 ? a0 : z == 1 ? a1 : z == 2 ? a2 : a3;
  u16* o       = z == 0 ? o0 : z == 1 ? o1 : z == 2 ? o2 : o3;
  int i = blockIdx.x * 256 + threadIdx.x;
  if (i >= n4) return;
  float4 v = ((const float4*)a)[i];
  ushort4 r; r.x = f2bf(v.x); r.y = f2bf(v.y); r.z = f2bf(v.z); r.w = f2bf(v.w);
  ((ushort4*)o)[i] = r;
}

// ---------------- GEMM: C[M=4096,N=1024] = A[M,K=1024] * W[N,K]^T ------------
// MODE 0: write bf16 to [B,H,T,DK]   (Q with scale, K)
// MODE 1: write bf16 to [B,H,DK,T]   (V transposed)
// MODE 2: write f32  to d_out, + bias[n]
template<int MODE>
__global__ __launch_bounds__(256) void gemm_bt(const u16* __restrict__ A, const u16* __restrict__ W,
                                               u16* __restrict__ obf, float* __restrict__ of,
                                               const float* __restrict__ bias, float scale) {
  __shared__ u16 As[128 * 32];
  __shared__ u16 Bs[128 * 32];
  int tid = threadIdx.x;
  int lane = tid & 63, wave = tid >> 6;
  int ln = lane & 15, g = lane >> 4;
  int m0 = blockIdx.x * 128, n0 = blockIdx.y * 128;
  int wm = (wave >> 1) * 64, wn = (wave & 1) * 64;
  f32x4 acc[4][4] = {};

  int c0 = tid, c1 = tid + 256;            // 512 16B chunks per 8KB tile
  const u16* gA0 = A + (size_t)(m0 + (c0 >> 2)) * 1024 + (c0 & 3) * 8;
  const u16* gA1 = A + (size_t)(m0 + (c1 >> 2)) * 1024 + (c1 & 3) * 8;
  const u16* gW0 = W + (size_t)(n0 + (c0 >> 2)) * 1024 + (c0 & 3) * 8;
  const u16* gW1 = W + (size_t)(n0 + (c1 >> 2)) * 1024 + (c1 & 3) * 8;

  for (int k0 = 0; k0 < 1024; k0 += 32) {
    __builtin_amdgcn_global_load_lds((const __attribute__((address_space(1))) void*)(gA0 + k0),
                                     (__attribute__((address_space(3))) void*)(As + c0 * 8), 16, 0, 0);
    __builtin_amdgcn_global_load_lds((const __attribute__((address_space(1))) void*)(gA1 + k0),
                                     (__attribute__((address_space(3))) void*)(As + c1 * 8), 16, 0, 0);
    __builtin_amdgcn_global_load_lds((const __attribute__((address_space(1))) void*)(gW0 + k0),
                                     (__attribute__((address_space(3))) void*)(Bs + c0 * 8), 16, 0, 0);
    __builtin_amdgcn_global_load_lds((const __attribute__((address_space(1))) void*)(gW1 + k0),
                                     (__attribute__((address_space(3))) void*)(Bs + c1 * 8), 16, 0, 0);
    __syncthreads();
    bf16x8 af[4], bfr[4];
#pragma unroll
    for (int mi = 0; mi < 4; ++mi) af[mi]  = *(const bf16x8*)&As[(wm + mi * 16 + ln) * 32 + g * 8];
#pragma unroll
    for (int ni = 0; ni < 4; ++ni) bfr[ni] = *(const bf16x8*)&Bs[(wn + ni * 16 + ln) * 32 + g * 8];
#pragma unroll
    for (int mi = 0; mi < 4; ++mi)
#pragma unroll
      for (int ni = 0; ni < 4; ++ni)
        acc[mi][ni] = mfma16(af[mi], bfr[ni], acc[mi][ni]);
    __syncthreads();
  }

#pragma unroll
  for (int mi = 0; mi < 4; ++mi)
#pragma unroll
    for (int ni = 0; ni < 4; ++ni)
#pragma unroll
      for (int r = 0; r < 4; ++r) {
        int gm = m0 + wm + mi * 16 + g * 4 + r;   // token index (C/D: row=(lane>>4)*4+r)
        int gn = n0 + wn + ni * 16 + ln;          // feature index (col=lane&15)
        float v = acc[mi][ni][r] * scale;
        if (MODE == 2) {
          of[(size_t)gm * 1024 + gn] = v + bias[gn];
        } else if (MODE == 0) {
          // [B,H,T,DK]
          obf[((((size_t)(gm >> 11)) * Hc + (gn >> 6)) * Tc + (gm & 2047)) * DKc + (gn & 63)] = f2bf(v);
        } else {
          // [B,H,DK,T]  (V^T)
          obf[((((size_t)(gm >> 11)) * Hc + (gn >> 6)) * DKc + (gn & 63)) * Tc + (gm & 2047)] = f2bf(v);
        }
      }
}

// ---------------- Flash attention with on-the-fly ALiBi ----------------------
// grid: (qb = T/64, bh = B*H).  4 waves, each owns 16 q-rows.
// Q pre-scaled by (1/8)*log2e at projection; slope pre-multiplied by log2e;
// softmax done in base-2 (v_exp_f32 native).
__global__ __launch_bounds__(256) void flash_attn(const u16* __restrict__ Qh, const u16* __restrict__ Kh,
                                                  const u16* __restrict__ VT, u16* __restrict__ O) {
  __shared__ u16 P_lds[4][16][72];   // 72 stride: 144B rows = 16B aligned, 2-way conflict max
  int qb = blockIdx.x, bh = blockIdx.y;
  int b = bh >> 4, h = bh & (Hc - 1);
  int tid = threadIdx.x, wave = tid >> 6, lane = tid & 63;
  int ln = lane & 15, g = lane >> 4;
  float slope2 = exp2f(-0.5f * (float)(h + 1)) * LOG2E;   // slope_h * log2(e)

  int qrow_base = qb * 64 + wave * 16;
  const u16* Qp = Qh + ((size_t)bh * Tc + qrow_base + ln) * DKc;
  bf16x8 qf0 = *(const bf16x8*)&Qp[g * 8];
  bf16x8 qf1 = *(const bf16x8*)&Qp[32 + g * 8];

  f32x4 accO[4] = {};            // rows g*4+r, cols nd*16+ln (d-dim)
  float Mx[4], Lx[4];
#pragma unroll
  for (int r = 0; r < 4; ++r) { Mx[r] = -1e30f; Lx[r] = 0.f; }

  int nkv = qb + 1;              // causal: only blocks with ks <= q_max
  for (int kb = 0; kb < nkv; ++kb) {
    int ks = kb * 64;
    // ---- S = Q K^T (pre-scaled, base-2 domain) ----
    f32x4 s[4] = {};
    const u16* Kp = Kh + ((size_t)bh * Tc + ks) * DKc;
#pragma unroll
    for (int j = 0; j < 4; ++j) {
      const u16* Kr = Kp + (j * 16 + ln) * DKc;
      bf16x8 kf0 = *(const bf16x8*)&Kr[g * 8];
      bf16x8 kf1 = *(const bf16x8*)&Kr[32 + g * 8];
      s[j] = mfma16(qf0, kf0, s[j]);
      s[j] = mfma16(qf1, kf1, s[j]);
    }
    // ---- ALiBi bias + causal mask + online softmax ----
    float pj[4][4];
#pragma unroll
    for (int r = 0; r < 4; ++r) {
      int qg = qrow_base + g * 4 + r;
      float m = -1e30f;
#pragma unroll
      for (int j = 0; j < 4; ++j) {
        int kg = ks + j * 16 + ln;
        float vv = s[j][r] + slope2 * (float)(kg - qg);
        vv = (kg > qg) ? -1e30f : vv;
        pj[j][r] = vv;
        m = fmaxf(m, vv);
      }
#pragma unroll
      for (int off = 1; off < 16; off <<= 1) m = fmaxf(m, __shfl_xor(m, off, 64));
      float newM = fmaxf(Mx[r], m);
      float sc = __builtin_amdgcn_exp2f(Mx[r] - newM);
      Mx[r] = newM;
      float rs = 0.f;
#pragma unroll
      for (int j = 0; j < 4; ++j) {
        float p = __builtin_amdgcn_exp2f(pj[j][r] - newM);
        pj[j][r] = p;
        rs += p;
      }
#pragma unroll
      for (int off = 1; off < 16; off <<= 1) rs += __shfl_xor(rs, off, 64);
      Lx[r] = Lx[r] * sc + rs;
#pragma unroll
      for (int nd = 0; nd < 4; ++nd) accO[nd][r] *= sc;
    }
    // ---- P -> LDS (bf16), per-wave region, no barrier needed ----
#pragma unroll
    for (int r = 0; r < 4; ++r)
#pragma unroll
      for (int j = 0; j < 4; ++j)
        P_lds[wave][g * 4 + r][j * 16 + ln] = f2bf(pj[j][r]);
    // ---- O += P V  (V^T layout: contiguous along T) ----
#pragma unroll
    for (int kk = 0; kk < 2; ++kk) {
      bf16x8 pa = *(const bf16x8*)&P_lds[wave][ln][kk * 32 + g * 8];
#pragma unroll
      for (int nd = 0; nd < 4; ++nd) {
        const u16* Vp = VT + ((size_t)bh * DKc + nd * 16 + ln) * Tc + ks + kk * 32 + g * 8;
        bf16x8 vf = *(const bf16x8*)Vp;
        accO[nd] = mfma16(pa, vf, accO[nd]);
      }
    }
  }
  // ---- epilogue: O /= L, write [B,T,D] bf16 ----
#pragma unroll
  for (int nd = 0; nd < 4; ++nd)
#pragma unroll
    for (int r = 0; r < 4; ++r) {
      int t = qb * 64 + wave * 16 + g * 4 + r;
      int dcol = h * 64 + nd * 16 + ln;
      O[((size_t)(b * Tc + t)) * Dc + dcol] = f2bf(accO[nd][r] / Lx[r]);
    }
}

// -----------------------------------------------------------------------------
extern "C" void kernel_launch(void* const* d_in, const int* in_sizes, int n_in,
                              void* d_out, int out_size, void* d_ws, size_t ws_size,
                              hipStream_t stream) {
  const float* q  = (const float*)d_in[0];
  const float* k  = (const float*)d_in[1];
  const float* v  = (const float*)d_in[2];
  // d_in[3] = alibi_bias [H,T,T] — intentionally unused (computed on the fly)
  const float* wq = (const float*)d_in[4];
  const float* wk = (const float*)d_in[5];
  const float* wv = (const float*)d_in[6];
  const float* wo = (const float*)d_in[7];
  const float* bo = (const float*)d_in[8];

  char* ws = (char*)d_ws;
  const size_t MB = 1024 * 1024;
  u16* Xq = (u16*)(ws + 0 * MB);    // [4096,1024] bf16, 8MB each
  u16* Xk = (u16*)(ws + 8 * MB);
  u16* Xv = (u16*)(ws + 16 * MB);
  u16* Wq = (u16*)(ws + 24 * MB);   // [1024,1024] bf16, 2MB each
  u16* Wk = (u16*)(ws + 26 * MB);
  u16* Wv = (u16*)(ws + 28 * MB);
  u16* Wo = (u16*)(ws + 30 * MB);
  u16* Qh = (u16*)(ws + 32 * MB);   // [B,H,T,DK] bf16
  u16* Kh = (u16*)(ws + 40 * MB);   // [B,H,T,DK]
  u16* VT = (u16*)(ws + 48 * MB);   // [B,H,DK,T]
  u16* Ob = (u16*)(ws + 56 * MB);   // [B,T,D]
  float* out = (float*)d_out;

  // f32 -> bf16
  conv_kernel<<<dim3(4096, 1, 3), 256, 0, stream>>>(q, k, v, nullptr, Xq, Xk, Xv, nullptr,
                                                    (BTc * Dc) / 4);
  conv_kernel<<<dim3(1024, 1, 4), 256, 0, stream>>>(wq, wk, wv, wo, Wq, Wk, Wv, Wo,
                                                    (Dc * Dc) / 4);
  // projections (Q folds 1/sqrt(DK) * log2e for base-2 softmax)
  gemm_bt<0><<<dim3(32, 8), 256, 0, stream>>>(Xq, Wq, Qh, nullptr, nullptr, 0.125f * LOG2E);
  gemm_bt<0><<<dim3(32, 8), 256, 0, stream>>>(Xk, Wk, Kh, nullptr, nullptr, 1.0f);
  gemm_bt<1><<<dim3(32, 8), 256, 0, stream>>>(Xv, Wv, VT, nullptr, nullptr, 1.0f);
  // attention
  flash_attn<<<dim3(Tc / 64, Bc * Hc), 256, 0, stream>>>(Qh, Kh, VT, Ob);
  // output projection + bias -> f32 d_out
  gemm_bt<2><<<dim3(32, 8), 256, 0, stream>>>(Ob, Wo, nullptr, out, bo, 1.0f);
}

// Round 2
// 212.439 us; speedup vs baseline: 1.5871x; 1.5871x over previous
//
#include <hip/hip_runtime.h>
#include <hip/hip_bf16.h>
#include <stdint.h>

// Problem constants (B=2, T=2048, D=1024, H=16, DK=64)
#define Bc   2
#define Tc   2048
#define Dc   1024
#define Hc   16
#define DKc  64
#define BTc  4096
#define LOG2E 1.44269504088896f

typedef unsigned short u16;
typedef __attribute__((ext_vector_type(8))) short bf16x8;
typedef __attribute__((ext_vector_type(4))) float f32x4;

static __device__ __forceinline__ u16 f2bf(float f) {
  union { float f; unsigned u; } v; v.f = f;
  unsigned r = v.u + 0x7fffu + ((v.u >> 16) & 1u);   // RNE
  return (u16)(r >> 16);
}

static __device__ __forceinline__ f32x4 mfma16(bf16x8 a, bf16x8 b, f32x4 c) {
  return __builtin_amdgcn_mfma_f32_16x16x32_bf16(a, b, c, 0, 0, 0);
}

// ---------------- f32 -> bf16 conversion (grid.z selects tensor) -------------
__global__ void conv_kernel(const float* __restrict__ a0, const float* __restrict__ a1,
                            const float* __restrict__ a2, const float* __restrict__ a3,
                            u16* __restrict__ o0, u16* __restrict__ o1,
                            u16* __restrict__ o2, u16* __restrict__ o3, int n4) {
  int z = blockIdx.z;
  const float* a = z == 0 ? a0 : z == 1 ? a1 : z == 2 ? a2 : a3;
  u16* o       = z == 0 ? o0 : z == 1 ? o1 : z == 2 ? o2 : o3;
  int i = blockIdx.x * 256 + threadIdx.x;
  if (i >= n4) return;
  float4 v = ((const float4*)a)[i];
  ushort4 r; r.x = f2bf(v.x); r.y = f2bf(v.y); r.z = f2bf(v.z); r.w = f2bf(v.w);
  ((ushort4*)o)[i] = r;
}

// ============= shared GEMM body: C[128,128] tile of A[M,K=1024]*W[N,K]^T =====
// As/Bs layout: [row][32] per K-slab; LDS reads are uniform 8/bank (b128 opt).
#define GEMM_BODY(A, W)                                                                              \
  __shared__ u16 As[128 * 32];                                                                       \
  __shared__ u16 Bs[128 * 32];                                                                       \
  int tid = threadIdx.x;                                                                             \
  int lane = tid & 63, wave = tid >> 6;                                                              \
  int ln = lane & 15, g = lane >> 4;                                                                 \
  int m0 = blockIdx.x * 128, n0 = blockIdx.y * 128;                                                  \
  int wm = (wave >> 1) * 64, wn = (wave & 1) * 64;                                                   \
  f32x4 acc[4][4] = {};                                                                              \
  int c0 = tid, c1 = tid + 256;                                                                      \
  const u16* gA0 = (A) + (size_t)(m0 + (c0 >> 2)) * 1024 + (c0 & 3) * 8;                             \
  const u16* gA1 = (A) + (size_t)(m0 + (c1 >> 2)) * 1024 + (c1 & 3) * 8;                             \
  const u16* gW0 = (W) + (size_t)(n0 + (c0 >> 2)) * 1024 + (c0 & 3) * 8;                             \
  const u16* gW1 = (W) + (size_t)(n0 + (c1 >> 2)) * 1024 + (c1 & 3) * 8;                             \
  for (int k0 = 0; k0 < 1024; k0 += 32) {                                                            \
    __builtin_amdgcn_global_load_lds((const __attribute__((address_space(1))) void*)(gA0 + k0),      \
                                     (__attribute__((address_space(3))) void*)(As + c0 * 8), 16, 0, 0); \
    __builtin_amdgcn_global_load_lds((const __attribute__((address_space(1))) void*)(gA1 + k0),      \
                                     (__attribute__((address_space(3))) void*)(As + c1 * 8), 16, 0, 0); \
    __builtin_amdgcn_global_load_lds((const __attribute__((address_space(1))) void*)(gW0 + k0),      \
                                     (__attribute__((address_space(3))) void*)(Bs + c0 * 8), 16, 0, 0); \
    __builtin_amdgcn_global_load_lds((const __attribute__((address_space(1))) void*)(gW1 + k0),      \
                                     (__attribute__((address_space(3))) void*)(Bs + c1 * 8), 16, 0, 0); \
    __syncthreads();                                                                                 \
    bf16x8 af[4], bfr[4];                                                                            \
    _Pragma("unroll") for (int mi = 0; mi < 4; ++mi)                                                 \
        af[mi] = *(const bf16x8*)&As[(wm + mi * 16 + ln) * 32 + g * 8];                              \
    _Pragma("unroll") for (int ni = 0; ni < 4; ++ni)                                                 \
        bfr[ni] = *(const bf16x8*)&Bs[(wn + ni * 16 + ln) * 32 + g * 8];                             \
    _Pragma("unroll") for (int mi = 0; mi < 4; ++mi)                                                 \
      _Pragma("unroll") for (int ni = 0; ni < 4; ++ni)                                               \
        acc[mi][ni] = mfma16(af[mi], bfr[ni], acc[mi][ni]);                                          \
    __syncthreads();                                                                                 \
  }

// ---------- fused Q/K/V projection: grid.z picks tensor (3 blocks/CU) --------
__global__ __launch_bounds__(256) void gemm_proj(const u16* __restrict__ Xq, const u16* __restrict__ Xk,
                                                 const u16* __restrict__ Xv, const u16* __restrict__ Wq,
                                                 const u16* __restrict__ Wk, const u16* __restrict__ Wv,
                                                 u16* __restrict__ Qh, u16* __restrict__ Kh,
                                                 u16* __restrict__ VTo) {
  int z = blockIdx.z;
  const u16* A = z == 0 ? Xq : z == 1 ? Xk : Xv;
  const u16* W = z == 0 ? Wq : z == 1 ? Wk : Wv;
  u16* outp    = z == 0 ? Qh : z == 1 ? Kh : VTo;
  float scale = (z == 0) ? 0.125f * LOG2E : 1.0f;   // fold 1/sqrt(DK)*log2e into Q
  GEMM_BODY(A, W)
#pragma unroll
  for (int mi = 0; mi < 4; ++mi)
#pragma unroll
    for (int ni = 0; ni < 4; ++ni)
#pragma unroll
      for (int r = 0; r < 4; ++r) {
        int gm = m0 + wm + mi * 16 + g * 4 + r;   // token
        int gn = n0 + wn + ni * 16 + ln;          // feature
        u16 v = f2bf(acc[mi][ni][r] * scale);
        size_t bhead = ((size_t)(gm >> 11)) * Hc + (gn >> 6);
        if (z == 2)   // [B,H,DK,T]  (V^T)
          outp[(bhead * DKc + (gn & 63)) * Tc + (gm & 2047)] = v;
        else          // [B,H,T,DK]
          outp[(bhead * Tc + (gm & 2047)) * DKc + (gn & 63)] = v;
      }
}

// ---------- output projection + bias -> f32 ----------------------------------
__global__ __launch_bounds__(256) void gemm_out(const u16* __restrict__ Ain, const u16* __restrict__ W,
                                                float* __restrict__ of, const float* __restrict__ bias) {
  GEMM_BODY(Ain, W)
#pragma unroll
  for (int mi = 0; mi < 4; ++mi)
#pragma unroll
    for (int ni = 0; ni < 4; ++ni)
#pragma unroll
      for (int r = 0; r < 4; ++r) {
        int gm = m0 + wm + mi * 16 + g * 4 + r;
        int gn = n0 + wn + ni * 16 + ln;
        of[(size_t)gm * 1024 + gn] = acc[mi][ni][r] + bias[gn];
      }
}

// ---------------- Flash attention with on-the-fly ALiBi ----------------------
// grid: (qb = T/64 reversed, bh = B*H).  4 waves x 16 q-rows.
// K/V tiles staged cooperatively in LDS (double-buffered, global_load_lds,
// XOR-swizzled via pre-swizzled global source — rule #21).
__global__ __launch_bounds__(256) void flash_attn(const u16* __restrict__ Qh, const u16* __restrict__ Kh,
                                                  const u16* __restrict__ VT, u16* __restrict__ O) {
  __shared__ u16 Ks[2][64 * 64];     // [kv_row][dk], rows 128B, XOR-swizzled
  __shared__ u16 Vs[2][64 * 64];     // [dk][t_off], rows 128B, XOR-swizzled
  __shared__ u16 P_lds[4][16][72];   // per-wave P tile, stride 144B
  int qb = (int)gridDim.x - 1 - (int)blockIdx.x;   // long (causal) blocks first
  int bh = blockIdx.y;
  int b = bh >> 4, h = bh & (Hc - 1);
  int tid = threadIdx.x, wave = tid >> 6, lane = tid & 63;
  int ln = lane & 15, g = lane >> 4;
  float slope2 = exp2f(-0.5f * (float)(h + 1)) * LOG2E;   // slope_h * log2(e)

  const u16* gK = Kh + (size_t)bh * Tc * DKc;
  const u16* gV = VT + (size_t)bh * DKc * Tc;
  // staging: 512 16B chunks/tile, 2 per thread; source pre-swizzled so that a
  // linear LDS dest + swizzled read form the same involution (byte^=(row&7)<<4)
  int c0 = tid, c1 = tid + 256;
  int r0 = c0 >> 3, r1 = c1 >> 3;
  int e0 = ((c0 & 7) << 3) ^ ((r0 & 7) << 3);
  int e1 = ((c1 & 7) << 3) ^ ((r1 & 7) << 3);
  size_t kO0 = (size_t)r0 * DKc + e0, kO1 = (size_t)r1 * DKc + e1;
  size_t vO0 = (size_t)r0 * Tc + e0, vO1 = (size_t)r1 * Tc + e1;

#define AS1 const __attribute__((address_space(1))) void*
#define AS3 __attribute__((address_space(3))) void*
#define STAGE(bufi, ks_) do {                                                                  \
    __builtin_amdgcn_global_load_lds((AS1)(gK + (size_t)(ks_) * DKc + kO0),                    \
                                     (AS3)(&Ks[bufi][c0 * 8]), 16, 0, 0);                      \
    __builtin_amdgcn_global_load_lds((AS1)(gK + (size_t)(ks_) * DKc + kO1),                    \
                                     (AS3)(&Ks[bufi][c1 * 8]), 16, 0, 0);                      \
    __builtin_amdgcn_global_load_lds((AS1)(gV + (size_t)(ks_) + vO0),                          \
                                     (AS3)(&Vs[bufi][c0 * 8]), 16, 0, 0);                      \
    __builtin_amdgcn_global_load_lds((AS1)(gV + (size_t)(ks_) + vO1),                          \
                                     (AS3)(&Vs[bufi][c1 * 8]), 16, 0, 0);                      \
  } while (0)

  int qrow_base = qb * 64 + wave * 16;
  const u16* Qp = Qh + ((size_t)bh * Tc + qrow_base + ln) * DKc;
  bf16x8 qf0 = *(const bf16x8*)&Qp[g * 8];
  bf16x8 qf1 = *(const bf16x8*)&Qp[32 + g * 8];

  f32x4 accO[4] = {};            // rows g*4+r, cols nd*16+ln (d-dim)
  float Mx[4], Lx[4];
#pragma unroll
  for (int r = 0; r < 4; ++r) { Mx[r] = -1e30f; Lx[r] = 0.f; }

  int nkv = qb + 1;              // causal
  STAGE(0, 0);
  __syncthreads();               // drains vmcnt(0): tile 0 ready
  int buf = 0;
  for (int kb = 0; kb < nkv; ++kb) {
    int ks = kb * 64;
    if (kb + 1 < nkv) STAGE(buf ^ 1, ks + 64);   // prefetch hides under compute
    // ---- S = Q K^T (pre-scaled, base-2 domain) ----
    f32x4 s[4] = {};
#pragma unroll
    for (int j = 0; j < 4; ++j) {
      int row = j * 16 + ln, sw = (row & 7) << 3;
      bf16x8 kf0 = *(const bf16x8*)&Ks[buf][row * DKc + ((g * 8) ^ sw)];
      bf16x8 kf1 = *(const bf16x8*)&Ks[buf][row * DKc + ((32 + g * 8) ^ sw)];
      s[j] = mfma16(qf0, kf0, s[j]);
      s[j] = mfma16(qf1, kf1, s[j]);
    }
    // ---- ALiBi bias + causal mask + online softmax ----
    float pj[4][4];
#pragma unroll
    for (int r = 0; r < 4; ++r) {
      int qg = qrow_base + g * 4 + r;
      float m = -1e30f;
#pragma unroll
      for (int j = 0; j < 4; ++j) {
        int kg = ks + j * 16 + ln;
        float vv = s[j][r] + slope2 * (float)(kg - qg);
        vv = (kg > qg) ? -1e30f : vv;
        pj[j][r] = vv;
        m = fmaxf(m, vv);
      }
#pragma unroll
      for (int off = 1; off < 16; off <<= 1) m = fmaxf(m, __shfl_xor(m, off, 64));
      float newM = fmaxf(Mx[r], m);
      float sc = __builtin_amdgcn_exp2f(Mx[r] - newM);
      Mx[r] = newM;
      float rs = 0.f;
#pragma unroll
      for (int j = 0; j < 4; ++j) {
        float p = __builtin_amdgcn_exp2f(pj[j][r] - newM);
        pj[j][r] = p;
        rs += p;
      }
#pragma unroll
      for (int off = 1; off < 16; off <<= 1) rs += __shfl_xor(rs, off, 64);
      Lx[r] = Lx[r] * sc + rs;
#pragma unroll
      for (int nd = 0; nd < 4; ++nd) accO[nd][r] *= sc;
    }
    // ---- P -> LDS (bf16), per-wave region ----
#pragma unroll
    for (int r = 0; r < 4; ++r)
#pragma unroll
      for (int j = 0; j < 4; ++j)
        P_lds[wave][g * 4 + r][j * 16 + ln] = f2bf(pj[j][r]);
    // ---- O += P V  (V^T in LDS: contiguous along T, swizzled) ----
#pragma unroll
    for (int kk = 0; kk < 2; ++kk) {
      bf16x8 pa = *(const bf16x8*)&P_lds[wave][ln][kk * 32 + g * 8];
#pragma unroll
      for (int nd = 0; nd < 4; ++nd) {
        int d = nd * 16 + ln, o = kk * 32 + g * 8;
        bf16x8 vf = *(const bf16x8*)&Vs[buf][d * DKc + (o ^ ((d & 7) << 3))];
        accO[nd] = mfma16(pa, vf, accO[nd]);
      }
    }
    __syncthreads();             // drains vmcnt(0): next tile ready; buf free
    buf ^= 1;
  }
  // ---- epilogue: O /= L, write [B,T,D] bf16 ----
#pragma unroll
  for (int nd = 0; nd < 4; ++nd)
#pragma unroll
    for (int r = 0; r < 4; ++r) {
      int t = qb * 64 + wave * 16 + g * 4 + r;
      int dcol = h * 64 + nd * 16 + ln;
      O[((size_t)(b * Tc + t)) * Dc + dcol] = f2bf(accO[nd][r] / Lx[r]);
    }
#undef STAGE
#undef AS1
#undef AS3
}

// -----------------------------------------------------------------------------
extern "C" void kernel_launch(void* const* d_in, const int* in_sizes, int n_in,
                              void* d_out, int out_size, void* d_ws, size_t ws_size,
                              hipStream_t stream) {
  const float* q  = (const float*)d_in[0];
  const float* k  = (const float*)d_in[1];
  const float* v  = (const float*)d_in[2];
  // d_in[3] = alibi_bias [H,T,T] — intentionally unused (computed on the fly)
  const float* wq = (const float*)d_in[4];
  const float* wk = (const float*)d_in[5];
  const float* wv = (const float*)d_in[6];
  const float* wo = (const float*)d_in[7];
  const float* bo = (const float*)d_in[8];

  char* ws = (char*)d_ws;
  const size_t MB = 1024 * 1024;
  u16* Xq = (u16*)(ws + 0 * MB);    // [4096,1024] bf16
  u16* Xk = (u16*)(ws + 8 * MB);
  u16* Xv = (u16*)(ws + 16 * MB);
  u16* Wq = (u16*)(ws + 24 * MB);   // [1024,1024] bf16
  u16* Wk = (u16*)(ws + 26 * MB);
  u16* Wv = (u16*)(ws + 28 * MB);
  u16* Wo = (u16*)(ws + 30 * MB);
  u16* Qh = (u16*)(ws + 32 * MB);   // [B,H,T,DK] bf16
  u16* Kh = (u16*)(ws + 40 * MB);   // [B,H,T,DK]
  u16* VT = (u16*)(ws + 48 * MB);   // [B,H,DK,T]
  u16* Ob = (u16*)(ws + 56 * MB);   // [B,T,D]
  float* out = (float*)d_out;

  // f32 -> bf16
  conv_kernel<<<dim3(4096, 1, 3), 256, 0, stream>>>(q, k, v, nullptr, Xq, Xk, Xv, nullptr,
                                                    (BTc * Dc) / 4);
  conv_kernel<<<dim3(1024, 1, 4), 256, 0, stream>>>(wq, wk, wv, wo, Wq, Wk, Wv, Wo,
                                                    (Dc * Dc) / 4);
  // fused Q/K/V projections (one dispatch, 768 blocks = 3 blocks/CU)
  gemm_proj<<<dim3(32, 8, 3), 256, 0, stream>>>(Xq, Xk, Xv, Wq, Wk, Wv, Qh, Kh, VT);
  // attention
  flash_attn<<<dim3(Tc / 64, Bc * Hc), 256, 0, stream>>>(Qh, Kh, VT, Ob);
  // output projection + bias -> f32 d_out
  gemm_out<<<dim3(32, 8), 256, 0, stream>>>(Ob, Wo, out, bo);
}

// Round 3
// 167.712 us; speedup vs baseline: 2.0103x; 1.2667x over previous
//
#include <hip/hip_runtime.h>
#include <hip/hip_bf16.h>
#include <stdint.h>

// Problem constants (B=2, T=2048, D=1024, H=16, DK=64)
#define Bc   2
#define Tc   2048
#define Dc   1024
#define Hc   16
#define DKc  64
#define BTc  4096
#define LOG2E 1.44269504088896f

typedef unsigned short u16;
typedef unsigned int u32;
typedef __attribute__((ext_vector_type(8))) short bf16x8;
typedef __attribute__((ext_vector_type(4))) float f32x4;
typedef __attribute__((ext_vector_type(2))) u32 u32x2;

static __device__ __forceinline__ u16 f2bf(float f) {
  union { float f; unsigned u; } v; v.f = f;
  unsigned r = v.u + 0x7fffu + ((v.u >> 16) & 1u);   // RNE
  return (u16)(r >> 16);
}

static __device__ __forceinline__ u32 cvt_pk_bf16(float lo, float hi) {
  u32 r;
  asm volatile("v_cvt_pk_bf16_f32 %0, %1, %2" : "=v"(r) : "v"(lo), "v"(hi));
  return r;
}

static __device__ __forceinline__ f32x4 mfma16(bf16x8 a, bf16x8 b, f32x4 c) {
  return __builtin_amdgcn_mfma_f32_16x16x32_bf16(a, b, c, 0, 0, 0);
}

// ---------------- f32 -> bf16 conversion (grid.z selects tensor) -------------
__global__ void conv_kernel(const float* __restrict__ a0, const float* __restrict__ a1,
                            const float* __restrict__ a2, const float* __restrict__ a3,
                            u16* __restrict__ o0, u16* __restrict__ o1,
                            u16* __restrict__ o2, u16* __restrict__ o3, int n4) {
  int z = blockIdx.z;
  const float* a = z == 0 ? a0 : z == 1 ? a1 : z == 2 ? a2 : a3;
  u16* o       = z == 0 ? o0 : z == 1 ? o1 : z == 2 ? o2 : o3;
  int i = blockIdx.x * 256 + threadIdx.x;
  if (i >= n4) return;
  float4 v = ((const float4*)a)[i];
  ushort4 r; r.x = f2bf(v.x); r.y = f2bf(v.y); r.z = f2bf(v.z); r.w = f2bf(v.w);
  ((ushort4*)o)[i] = r;
}

// ============= shared GEMM body: C[128,128] tile of A[M,K=1024]*W[N,K]^T =====
#define GEMM_BODY(A, W)                                                                              \
  __shared__ u16 As[128 * 32];                                                                       \
  __shared__ u16 Bs[128 * 32];                                                                       \
  int tid = threadIdx.x;                                                                             \
  int lane = tid & 63, wave = tid >> 6;                                                              \
  int ln = lane & 15, g = lane >> 4;                                                                 \
  int m0 = blockIdx.x * 128, n0 = blockIdx.y * 128;                                                  \
  int wm = (wave >> 1) * 64, wn = (wave & 1) * 64;                                                   \
  f32x4 acc[4][4] = {};                                                                              \
  int c0 = tid, c1 = tid + 256;                                                                      \
  const u16* gA0 = (A) + (size_t)(m0 + (c0 >> 2)) * 1024 + (c0 & 3) * 8;                             \
  const u16* gA1 = (A) + (size_t)(m0 + (c1 >> 2)) * 1024 + (c1 & 3) * 8;                             \
  const u16* gW0 = (W) + (size_t)(n0 + (c0 >> 2)) * 1024 + (c0 & 3) * 8;                             \
  const u16* gW1 = (W) + (size_t)(n0 + (c1 >> 2)) * 1024 + (c1 & 3) * 8;                             \
  for (int k0 = 0; k0 < 1024; k0 += 32) {                                                            \
    __builtin_amdgcn_global_load_lds((const __attribute__((address_space(1))) void*)(gA0 + k0),      \
                                     (__attribute__((address_space(3))) void*)(As + c0 * 8), 16, 0, 0); \
    __builtin_amdgcn_global_load_lds((const __attribute__((address_space(1))) void*)(gA1 + k0),      \
                                     (__attribute__((address_space(3))) void*)(As + c1 * 8), 16, 0, 0); \
    __builtin_amdgcn_global_load_lds((const __attribute__((address_space(1))) void*)(gW0 + k0),      \
                                     (__attribute__((address_space(3))) void*)(Bs + c0 * 8), 16, 0, 0); \
    __builtin_amdgcn_global_load_lds((const __attribute__((address_space(1))) void*)(gW1 + k0),      \
                                     (__attribute__((address_space(3))) void*)(Bs + c1 * 8), 16, 0, 0); \
    __syncthreads();                                                                                 \
    bf16x8 af[4], bfr[4];                                                                            \
    _Pragma("unroll") for (int mi = 0; mi < 4; ++mi)                                                 \
        af[mi] = *(const bf16x8*)&As[(wm + mi * 16 + ln) * 32 + g * 8];                              \
    _Pragma("unroll") for (int ni = 0; ni < 4; ++ni)                                                 \
        bfr[ni] = *(const bf16x8*)&Bs[(wn + ni * 16 + ln) * 32 + g * 8];                             \
    _Pragma("unroll") for (int mi = 0; mi < 4; ++mi)                                                 \
      _Pragma("unroll") for (int ni = 0; ni < 4; ++ni)                                               \
        acc[mi][ni] = mfma16(af[mi], bfr[ni], acc[mi][ni]);                                          \
    __syncthreads();                                                                                 \
  }

// ---------- fused Q/K/V projection: grid.z picks tensor (3 blocks/CU) --------
__global__ __launch_bounds__(256) void gemm_proj(const u16* __restrict__ Xq, const u16* __restrict__ Xk,
                                                 const u16* __restrict__ Xv, const u16* __restrict__ Wq,
                                                 const u16* __restrict__ Wk, const u16* __restrict__ Wv,
                                                 u16* __restrict__ Qh, u16* __restrict__ Kh,
                                                 u16* __restrict__ VTo) {
  int z = blockIdx.z;
  const u16* A = z == 0 ? Xq : z == 1 ? Xk : Xv;
  const u16* W = z == 0 ? Wq : z == 1 ? Wk : Wv;
  u16* outp    = z == 0 ? Qh : z == 1 ? Kh : VTo;
  float scale = (z == 0) ? 0.125f * LOG2E : 1.0f;   // fold 1/sqrt(DK)*log2e into Q
  GEMM_BODY(A, W)
#pragma unroll
  for (int mi = 0; mi < 4; ++mi)
#pragma unroll
    for (int ni = 0; ni < 4; ++ni)
#pragma unroll
      for (int r = 0; r < 4; ++r) {
        int gm = m0 + wm + mi * 16 + g * 4 + r;   // token
        int gn = n0 + wn + ni * 16 + ln;          // feature
        u16 v = f2bf(acc[mi][ni][r] * scale);
        size_t bhead = ((size_t)(gm >> 11)) * Hc + (gn >> 6);
        if (z == 2)   // [B,H,DK,T]  (V^T)
          outp[(bhead * DKc + (gn & 63)) * Tc + (gm & 2047)] = v;
        else          // [B,H,T,DK]
          outp[(bhead * Tc + (gm & 2047)) * DKc + (gn & 63)] = v;
      }
}

// ---------- output projection + bias -> f32 ----------------------------------
__global__ __launch_bounds__(256) void gemm_out(const u16* __restrict__ Ain, const u16* __restrict__ W,
                                                float* __restrict__ of, const float* __restrict__ bias) {
  GEMM_BODY(Ain, W)
#pragma unroll
  for (int mi = 0; mi < 4; ++mi)
#pragma unroll
    for (int ni = 0; ni < 4; ++ni)
#pragma unroll
      for (int r = 0; r < 4; ++r) {
        int gm = m0 + wm + mi * 16 + g * 4 + r;
        int gn = n0 + wn + ni * 16 + ln;
        of[(size_t)gm * 1024 + gn] = acc[mi][ni][r] + bias[gn];
      }
}

// ---------------- Flash attention, swapped-QK in-lane softmax ----------------
// grid: (qb reversed, bh). 4 waves x 16 q-rows. S^T = mfma(K,Q): lane holds
// 16 k-scores of ONE q-row (q = lane&15) -> softmax is register-local + 2 shfl.
__global__ __launch_bounds__(256) void flash_attn(const u16* __restrict__ Qh, const u16* __restrict__ Kh,
                                                  const u16* __restrict__ VT, u16* __restrict__ O) {
  __shared__ u16 Ks[2][64 * 64];     // [kv_row][dk], XOR-swizzled (byte^=(row&7)<<4)
  __shared__ u16 Vs[2][64 * 64];     // [dk][t_off], XOR-swizzled
  __shared__ u16 P_lds[4][16][64];   // [wave][q][k], XOR-swizzled (byte^=(q&7)<<4)
  int qb = (int)gridDim.x - 1 - (int)blockIdx.x;   // long (causal) blocks first
  int bh = blockIdx.y;
  int b = bh >> 4, h = bh & (Hc - 1);
  int tid = threadIdx.x, wave = tid >> 6, lane = tid & 63;
  int ln = lane & 15, g = lane >> 4;
  float slope2 = exp2f(-0.5f * (float)(h + 1)) * LOG2E;   // slope_h * log2(e)

  const u16* gK = Kh + (size_t)bh * Tc * DKc;
  const u16* gV = VT + (size_t)bh * DKc * Tc;
  // staging: pre-swizzled global source + linear LDS dest (rule #21)
  int c0 = tid, c1 = tid + 256;
  int r0 = c0 >> 3, r1 = c1 >> 3;
  int e0 = ((c0 & 7) << 3) ^ ((r0 & 7) << 3);
  int e1 = ((c1 & 7) << 3) ^ ((r1 & 7) << 3);
  size_t kO0 = (size_t)r0 * DKc + e0, kO1 = (size_t)r1 * DKc + e1;
  size_t vO0 = (size_t)r0 * Tc + e0, vO1 = (size_t)r1 * Tc + e1;

#define AS1 const __attribute__((address_space(1))) void*
#define AS3 __attribute__((address_space(3))) void*
#define STAGE(bufi, ks_) do {                                                                  \
    __builtin_amdgcn_global_load_lds((AS1)(gK + (size_t)(ks_) * DKc + kO0),                    \
                                     (AS3)(&Ks[bufi][c0 * 8]), 16, 0, 0);                      \
    __builtin_amdgcn_global_load_lds((AS1)(gK + (size_t)(ks_) * DKc + kO1),                    \
                                     (AS3)(&Ks[bufi][c1 * 8]), 16, 0, 0);                      \
    __builtin_amdgcn_global_load_lds((AS1)(gV + (size_t)(ks_) + vO0),                          \
                                     (AS3)(&Vs[bufi][c0 * 8]), 16, 0, 0);                      \
    __builtin_amdgcn_global_load_lds((AS1)(gV + (size_t)(ks_) + vO1),                          \
                                     (AS3)(&Vs[bufi][c1 * 8]), 16, 0, 0);                      \
  } while (0)

  int qrow_base = qb * 64 + wave * 16;
  int qg = qrow_base + ln;           // this lane's q-row
  int wv16ln = wave * 16 + ln;       // diag-mask threshold
  const u16* Qp = Qh + ((size_t)bh * Tc + qrow_base + ln) * DKc;
  bf16x8 qf0 = *(const bf16x8*)&Qp[g * 8];
  bf16x8 qf1 = *(const bf16x8*)&Qp[32 + g * 8];

  // per-lane ALiBi offsets for the k's this lane owns: k_local = j*16+g*4+r
  float vb[4][4];
#pragma unroll
  for (int j = 0; j < 4; ++j)
#pragma unroll
    for (int r = 0; r < 4; ++r)
      vb[j][r] = slope2 * (float)(j * 16 + g * 4 + r);

  f32x4 accO[4] = {};                // rows q=g*4+r (within wave tile), cols d=nd*16+ln
  float Mx = -1e30f, Lx = 0.f;       // per-lane running max/sum for q = qg

  int nkv = qb + 1;                  // causal
  STAGE(0, 0);
  __syncthreads();
  int buf = 0;

  auto fa_step = [&](int kb, bool diag) {
    int ks = kb * 64;
    if (kb + 1 < nkv) STAGE(buf ^ 1, ks + 64);   // prefetch hides under compute
    // ---- S^T = K Q^T : lane -> q=qg, k = ks + j*16 + g*4 + r ----
    f32x4 s[4] = {};
#pragma unroll
    for (int j = 0; j < 4; ++j) {
      int row = j * 16 + ln, sw = (row & 7) << 3;
      bf16x8 kf0 = *(const bf16x8*)&Ks[buf][row * DKc + ((g * 8) ^ sw)];
      bf16x8 kf1 = *(const bf16x8*)&Ks[buf][row * DKc + ((32 + g * 8) ^ sw)];
      s[j] = mfma16(kf0, qf0, s[j]);
      s[j] = mfma16(kf1, qf1, s[j]);
    }
    // ---- bias + (diag-only) mask; register-local max ----
    float vv[4][4];
    float mloc = -1e30f;
#pragma unroll
    for (int j = 0; j < 4; ++j)
#pragma unroll
      for (int r = 0; r < 4; ++r) {
        float t = s[j][r] + vb[j][r];
        if (diag) t = (j * 16 + g * 4 + r > wv16ln) ? -1e30f : t;
        vv[j][r] = t;
        mloc = fmaxf(mloc, t);
      }
    mloc = fmaxf(mloc, __shfl_xor(mloc, 16, 64));
    mloc = fmaxf(mloc, __shfl_xor(mloc, 32, 64));
    float cterm = slope2 * (float)(ks - qg);   // true score = vv + cterm
    float newM = fmaxf(Mx, mloc + cterm);
    float sc = __builtin_amdgcn_exp2f(Mx - newM);
    Mx = newM;
    float dsub = newM - cterm;
    float rs = 0.f;
#pragma unroll
    for (int j = 0; j < 4; ++j)
#pragma unroll
      for (int r = 0; r < 4; ++r) {
        float p = __builtin_amdgcn_exp2f(vv[j][r] - dsub);
        vv[j][r] = p;
        rs += p;
      }
    Lx = Lx * sc + rs;                 // cross-g reduce deferred to epilogue
    // broadcast rescale factors to output-row owners
    float scb[4];
#pragma unroll
    for (int r = 0; r < 4; ++r) scb[r] = __shfl(sc, g * 4 + r, 64);
#pragma unroll
    for (int nd = 0; nd < 4; ++nd)
#pragma unroll
      for (int r = 0; r < 4; ++r) accO[nd][r] *= scb[r];
    // ---- P -> LDS: lane's 4 consecutive-k values per j, packed bf16 ----
    char* Prow = (char*)&P_lds[wave][ln][0];
    int psw = (ln & 7) << 4;
#pragma unroll
    for (int j = 0; j < 4; ++j) {
      u32x2 w;
      w.x = cvt_pk_bf16(vv[j][0], vv[j][1]);
      w.y = cvt_pk_bf16(vv[j][2], vv[j][3]);
      *(u32x2*)(Prow + ((j * 32 + g * 8) ^ psw)) = w;
    }
    // ---- O += P V ----
#pragma unroll
    for (int kk = 0; kk < 2; ++kk) {
      bf16x8 pa = *(const bf16x8*)(Prow + ((kk * 64 + g * 16) ^ psw));
#pragma unroll
      for (int nd = 0; nd < 4; ++nd) {
        int d = nd * 16 + ln, o = kk * 32 + g * 8;
        bf16x8 vf = *(const bf16x8*)&Vs[buf][d * DKc + (o ^ ((d & 7) << 3))];
        accO[nd] = mfma16(pa, vf, accO[nd]);
      }
    }
    __syncthreads();                   // next tile staged; buf free
    buf ^= 1;
  };

  for (int kb = 0; kb < nkv - 1; ++kb) fa_step(kb, false);
  fa_step(nkv - 1, true);

  // ---- epilogue: finish L reduce, O /= L, write [B,T,D] bf16 ----
  float Lf = Lx + __shfl_xor(Lx, 16, 64);
  Lf = Lf + __shfl_xor(Lf, 32, 64);
  float linv[4];
#pragma unroll
  for (int r = 0; r < 4; ++r) linv[r] = 1.0f / __shfl(Lf, g * 4 + r, 64);
#pragma unroll
  for (int nd = 0; nd < 4; ++nd)
#pragma unroll
    for (int r = 0; r < 4; ++r) {
      int t = qb * 64 + wave * 16 + g * 4 + r;
      int dcol = h * 64 + nd * 16 + ln;
      O[((size_t)(b * Tc + t)) * Dc + dcol] = f2bf(accO[nd][r] * linv[r]);
    }
#undef STAGE
#undef AS1
#undef AS3
}

// -----------------------------------------------------------------------------
extern "C" void kernel_launch(void* const* d_in, const int* in_sizes, int n_in,
                              void* d_out, int out_size, void* d_ws, size_t ws_size,
                              hipStream_t stream) {
  const float* q  = (const float*)d_in[0];
  const float* k  = (const float*)d_in[1];
  const float* v  = (const float*)d_in[2];
  // d_in[3] = alibi_bias [H,T,T] — intentionally unused (computed on the fly)
  const float* wq = (const float*)d_in[4];
  const float* wk = (const float*)d_in[5];
  const float* wv = (const float*)d_in[6];
  const float* wo = (const float*)d_in[7];
  const float* bo = (const float*)d_in[8];

  char* ws = (char*)d_ws;
  const size_t MB = 1024 * 1024;
  u16* Xq = (u16*)(ws + 0 * MB);    // [4096,1024] bf16
  u16* Xk = (u16*)(ws + 8 * MB);
  u16* Xv = (u16*)(ws + 16 * MB);
  u16* Wq = (u16*)(ws + 24 * MB);   // [1024,1024] bf16
  u16* Wk = (u16*)(ws + 26 * MB);
  u16* Wv = (u16*)(ws + 28 * MB);
  u16* Wo = (u16*)(ws + 30 * MB);
  u16* Qh = (u16*)(ws + 32 * MB);   // [B,H,T,DK] bf16
  u16* Kh = (u16*)(ws + 40 * MB);   // [B,H,T,DK]
  u16* VT = (u16*)(ws + 48 * MB);   // [B,H,DK,T]
  u16* Ob = (u16*)(ws + 56 * MB);   // [B,T,D]
  float* out = (float*)d_out;

  // f32 -> bf16
  conv_kernel<<<dim3(4096, 1, 3), 256, 0, stream>>>(q, k, v, nullptr, Xq, Xk, Xv, nullptr,
                                                    (BTc * Dc) / 4);
  conv_kernel<<<dim3(1024, 1, 4), 256, 0, stream>>>(wq, wk, wv, wo, Wq, Wk, Wv, Wo,
                                                    (Dc * Dc) / 4);
  // fused Q/K/V projections (one dispatch, 768 blocks = 3 blocks/CU)
  gemm_proj<<<dim3(32, 8, 3), 256, 0, stream>>>(Xq, Xk, Xv, Wq, Wk, Wv, Qh, Kh, VT);
  // attention
  flash_attn<<<dim3(Tc / 64, Bc * Hc), 256, 0, stream>>>(Qh, Kh, VT, Ob);
  // output projection + bias -> f32 d_out
  gemm_out<<<dim3(32, 8), 256, 0, stream>>>(Ob, Wo, out, bo);
}

// Round 4
// 154.056 us; speedup vs baseline: 2.1885x; 1.0886x over previous
//
#include <hip/hip_runtime.h>
#include <hip/hip_bf16.h>
#include <stdint.h>

// Problem constants (B=2, T=2048, D=1024, H=16, DK=64)
#define Bc   2
#define Tc   2048
#define Dc   1024
#define Hc   16
#define DKc  64
#define BTc  4096
#define LOG2E 1.44269504088896f

typedef unsigned short u16;
typedef unsigned int u32;
typedef __attribute__((ext_vector_type(8))) short bf16x8;
typedef __attribute__((ext_vector_type(4))) float f32x4;
typedef __attribute__((ext_vector_type(2))) u32 u32x2;

static __device__ __forceinline__ u16 f2bf(float f) {
  union { float f; unsigned u; } v; v.f = f;
  unsigned r = v.u + 0x7fffu + ((v.u >> 16) & 1u);   // RNE
  return (u16)(r >> 16);
}

static __device__ __forceinline__ u32 cvt_pk_bf16(float lo, float hi) {
  u32 r;
  asm volatile("v_cvt_pk_bf16_f32 %0, %1, %2" : "=v"(r) : "v"(lo), "v"(hi));
  return r;
}

static __device__ __forceinline__ f32x4 mfma16(bf16x8 a, bf16x8 b, f32x4 c) {
  return __builtin_amdgcn_mfma_f32_16x16x32_bf16(a, b, c, 0, 0, 0);
}

// ------------- f32 -> bf16 conversion: one dispatch for all 7 tensors --------
// grid (4096+1024, 1, 4): bx<4096 -> X[z] (z<3), else -> W[z]
__global__ void conv_kernel(const float* __restrict__ q, const float* __restrict__ k,
                            const float* __restrict__ v, const float* __restrict__ wq,
                            const float* __restrict__ wk, const float* __restrict__ wv,
                            const float* __restrict__ wo,
                            u16* __restrict__ Xq, u16* __restrict__ Xk, u16* __restrict__ Xv,
                            u16* __restrict__ Wq, u16* __restrict__ Wk, u16* __restrict__ Wv,
                            u16* __restrict__ Wo) {
  int z = blockIdx.z, bx = blockIdx.x;
  const float* src; u16* dst; int i;
  if (bx < 4096) {
    if (z == 3) return;
    src = z == 0 ? q : z == 1 ? k : v;
    dst = z == 0 ? Xq : z == 1 ? Xk : Xv;
    i = bx * 256 + threadIdx.x;
  } else {
    src = z == 0 ? wq : z == 1 ? wk : z == 2 ? wv : wo;
    dst = z == 0 ? Wq : z == 1 ? Wk : z == 2 ? Wv : Wo;
    i = (bx - 4096) * 256 + threadIdx.x;
  }
  float4 f = ((const float4*)src)[i];
  ushort4 r; r.x = f2bf(f.x); r.y = f2bf(f.y); r.z = f2bf(f.z); r.w = f2bf(f.w);
  ((ushort4*)dst)[i] = r;
}

#define AS1 const __attribute__((address_space(1))) void*
#define AS3 __attribute__((address_space(3))) void*

// ---------- fused Q/K/V projection: grid.z picks tensor (3 blocks/CU) --------
__global__ __launch_bounds__(256) void gemm_proj(const u16* __restrict__ Xq, const u16* __restrict__ Xk,
                                                 const u16* __restrict__ Xv, const u16* __restrict__ Wq,
                                                 const u16* __restrict__ Wk, const u16* __restrict__ Wv,
                                                 u16* __restrict__ Qh, u16* __restrict__ Kh,
                                                 u16* __restrict__ VTo) {
  __shared__ u16 As[128 * 32];
  __shared__ u16 Bs[128 * 32];
  int z = blockIdx.z;
  const u16* A = z == 0 ? Xq : z == 1 ? Xk : Xv;
  const u16* W = z == 0 ? Wq : z == 1 ? Wk : Wv;
  u16* outp    = z == 0 ? Qh : z == 1 ? Kh : VTo;
  float scale = (z == 0) ? 0.125f * LOG2E : 1.0f;   // fold 1/sqrt(DK)*log2e into Q
  int tid = threadIdx.x;
  int lane = tid & 63, wave = tid >> 6;
  int ln = lane & 15, g = lane >> 4;
  int m0 = blockIdx.x * 128, n0 = blockIdx.y * 128;
  int wm = (wave >> 1) * 64, wn = (wave & 1) * 64;
  f32x4 acc[4][4] = {};
  int c0 = tid, c1 = tid + 256;
  const u16* gA0 = A + (size_t)(m0 + (c0 >> 2)) * 1024 + (c0 & 3) * 8;
  const u16* gA1 = A + (size_t)(m0 + (c1 >> 2)) * 1024 + (c1 & 3) * 8;
  const u16* gW0 = W + (size_t)(n0 + (c0 >> 2)) * 1024 + (c0 & 3) * 8;
  const u16* gW1 = W + (size_t)(n0 + (c1 >> 2)) * 1024 + (c1 & 3) * 8;
  for (int k0 = 0; k0 < 1024; k0 += 32) {
    __builtin_amdgcn_global_load_lds((AS1)(gA0 + k0), (AS3)(As + c0 * 8), 16, 0, 0);
    __builtin_amdgcn_global_load_lds((AS1)(gA1 + k0), (AS3)(As + c1 * 8), 16, 0, 0);
    __builtin_amdgcn_global_load_lds((AS1)(gW0 + k0), (AS3)(Bs + c0 * 8), 16, 0, 0);
    __builtin_amdgcn_global_load_lds((AS1)(gW1 + k0), (AS3)(Bs + c1 * 8), 16, 0, 0);
    __syncthreads();
    bf16x8 af[4], bfr[4];
#pragma unroll
    for (int mi = 0; mi < 4; ++mi) af[mi]  = *(const bf16x8*)&As[(wm + mi * 16 + ln) * 32 + g * 8];
#pragma unroll
    for (int ni = 0; ni < 4; ++ni) bfr[ni] = *(const bf16x8*)&Bs[(wn + ni * 16 + ln) * 32 + g * 8];
#pragma unroll
    for (int mi = 0; mi < 4; ++mi)
#pragma unroll
      for (int ni = 0; ni < 4; ++ni)
        acc[mi][ni] = mfma16(af[mi], bfr[ni], acc[mi][ni]);
    __syncthreads();
  }
  if (z == 2) {
    // V^T [B,H,DK,T]: r-consecutive values are t-adjacent -> pack 4 into 8B
#pragma unroll
    for (int mi = 0; mi < 4; ++mi)
#pragma unroll
      for (int ni = 0; ni < 4; ++ni) {
        int t0 = m0 + wm + mi * 16 + g * 4;
        int gn = n0 + wn + ni * 16 + ln;
        size_t bhead = ((size_t)(t0 >> 11)) * Hc + (gn >> 6);
        ushort4 pk;
        pk.x = f2bf(acc[mi][ni][0]); pk.y = f2bf(acc[mi][ni][1]);
        pk.z = f2bf(acc[mi][ni][2]); pk.w = f2bf(acc[mi][ni][3]);
        *(ushort4*)&outp[(bhead * DKc + (gn & 63)) * Tc + (t0 & 2047)] = pk;
      }
  } else {
#pragma unroll
    for (int mi = 0; mi < 4; ++mi)
#pragma unroll
      for (int ni = 0; ni < 4; ++ni)
#pragma unroll
        for (int r = 0; r < 4; ++r) {
          int gm = m0 + wm + mi * 16 + g * 4 + r;
          int gn = n0 + wn + ni * 16 + ln;
          size_t bhead = ((size_t)(gm >> 11)) * Hc + (gn >> 6);
          outp[(bhead * Tc + (gm & 2047)) * DKc + (gn & 63)] = f2bf(acc[mi][ni][r] * scale);
        }
  }
}

// ---------- output projection + bias -> f32 (BM=64: 512 blocks, 2/CU) --------
__global__ __launch_bounds__(256) void gemm_out(const u16* __restrict__ Ain, const u16* __restrict__ W,
                                                float* __restrict__ of, const float* __restrict__ bias) {
  __shared__ u16 As[64 * 32];
  __shared__ u16 Bs[128 * 32];
  int tid = threadIdx.x;
  int lane = tid & 63, wave = tid >> 6;
  int ln = lane & 15, g = lane >> 4;
  int m0 = blockIdx.x * 64, n0 = blockIdx.y * 128;
  int wm = (wave >> 1) * 32, wn = (wave & 1) * 64;
  f32x4 acc[2][4] = {};
  int ca = tid, cb0 = tid, cb1 = tid + 256;
  const u16* gA  = Ain + (size_t)(m0 + (ca  >> 2)) * 1024 + (ca  & 3) * 8;
  const u16* gW0 = W   + (size_t)(n0 + (cb0 >> 2)) * 1024 + (cb0 & 3) * 8;
  const u16* gW1 = W   + (size_t)(n0 + (cb1 >> 2)) * 1024 + (cb1 & 3) * 8;
  for (int k0 = 0; k0 < 1024; k0 += 32) {
    __builtin_amdgcn_global_load_lds((AS1)(gA  + k0), (AS3)(As + ca  * 8), 16, 0, 0);
    __builtin_amdgcn_global_load_lds((AS1)(gW0 + k0), (AS3)(Bs + cb0 * 8), 16, 0, 0);
    __builtin_amdgcn_global_load_lds((AS1)(gW1 + k0), (AS3)(Bs + cb1 * 8), 16, 0, 0);
    __syncthreads();
    bf16x8 af[2], bfr[4];
#pragma unroll
    for (int mi = 0; mi < 2; ++mi) af[mi]  = *(const bf16x8*)&As[(wm + mi * 16 + ln) * 32 + g * 8];
#pragma unroll
    for (int ni = 0; ni < 4; ++ni) bfr[ni] = *(const bf16x8*)&Bs[(wn + ni * 16 + ln) * 32 + g * 8];
#pragma unroll
    for (int mi = 0; mi < 2; ++mi)
#pragma unroll
      for (int ni = 0; ni < 4; ++ni)
        acc[mi][ni] = mfma16(af[mi], bfr[ni], acc[mi][ni]);
    __syncthreads();
  }
#pragma unroll
  for (int mi = 0; mi < 2; ++mi)
#pragma unroll
    for (int ni = 0; ni < 4; ++ni)
#pragma unroll
      for (int r = 0; r < 4; ++r) {
        int gm = m0 + wm + mi * 16 + g * 4 + r;
        int gn = n0 + wn + ni * 16 + ln;
        of[(size_t)gm * 1024 + gn] = acc[mi][ni][r] + bias[gn];
      }
}

// ---------------- Flash attention, swapped-QK + reversed kv (defer-max) ------
// grid: (qb reversed, bh). 4 waves x 16 q-rows. S^T = mfma(K,Q): lane holds
// 16 k-scores of ONE q-row (q = lane&15). kv iterates diagonal->0 so the
// running max is set on tile 1 and rescale is skipped almost always (T13).
__global__ __launch_bounds__(256) void flash_attn(const u16* __restrict__ Qh, const u16* __restrict__ Kh,
                                                  const u16* __restrict__ VT, u16* __restrict__ O) {
  __shared__ u16 Ks[2][64 * 64];     // [kv_row][dk], XOR-swizzled (byte^=(row&7)<<4)
  __shared__ u16 Vs[2][64 * 64];     // [dk][t_off], XOR-swizzled
  __shared__ u16 P_lds[4][16][64];   // [wave][q][k], XOR-swizzled (byte^=(q&7)<<4)
  int qb = (int)gridDim.x - 1 - (int)blockIdx.x;   // long (causal) blocks first
  int bh = blockIdx.y;
  int b = bh >> 4, h = bh & (Hc - 1);
  int tid = threadIdx.x, wave = tid >> 6, lane = tid & 63;
  int ln = lane & 15, g = lane >> 4;
  float slope2 = exp2f(-0.5f * (float)(h + 1)) * LOG2E;   // slope_h * log2(e)

  const u16* gK = Kh + (size_t)bh * Tc * DKc;
  const u16* gV = VT + (size_t)bh * DKc * Tc;
  // staging: pre-swizzled global source + linear LDS dest (rule #21)
  int c0 = tid, c1 = tid + 256;
  int r0 = c0 >> 3, r1 = c1 >> 3;
  int e0 = ((c0 & 7) << 3) ^ ((r0 & 7) << 3);
  int e1 = ((c1 & 7) << 3) ^ ((r1 & 7) << 3);
  size_t kO0 = (size_t)r0 * DKc + e0, kO1 = (size_t)r1 * DKc + e1;
  size_t vO0 = (size_t)r0 * Tc + e0, vO1 = (size_t)r1 * Tc + e1;

#define STAGE(bufi, ks_) do {                                                                  \
    __builtin_amdgcn_global_load_lds((AS1)(gK + (size_t)(ks_) * DKc + kO0),                    \
                                     (AS3)(&Ks[bufi][c0 * 8]), 16, 0, 0);                      \
    __builtin_amdgcn_global_load_lds((AS1)(gK + (size_t)(ks_) * DKc + kO1),                    \
                                     (AS3)(&Ks[bufi][c1 * 8]), 16, 0, 0);                      \
    __builtin_amdgcn_global_load_lds((AS1)(gV + (size_t)(ks_) + vO0),                          \
                                     (AS3)(&Vs[bufi][c0 * 8]), 16, 0, 0);                      \
    __builtin_amdgcn_global_load_lds((AS1)(gV + (size_t)(ks_) + vO1),                          \
                                     (AS3)(&Vs[bufi][c1 * 8]), 16, 0, 0);                      \
  } while (0)

  int qrow_base = qb * 64 + wave * 16;
  int qg = qrow_base + ln;           // this lane's q-row
  int wv16ln = wave * 16 + ln;       // diag-mask threshold
  const u16* Qp = Qh + ((size_t)bh * Tc + qrow_base + ln) * DKc;
  bf16x8 qf0 = *(const bf16x8*)&Qp[g * 8];
  bf16x8 qf1 = *(const bf16x8*)&Qp[32 + g * 8];

  // per-lane ALiBi offsets for the k's this lane owns: k_local = j*16+g*4+r
  float vb[4][4];
#pragma unroll
  for (int j = 0; j < 4; ++j)
#pragma unroll
    for (int r = 0; r < 4; ++r)
      vb[j][r] = slope2 * (float)(j * 16 + g * 4 + r);

  f32x4 accO[4] = {};                // rows q=g*4+r (within wave tile), cols d=nd*16+ln
  float Mx = -1e30f, Lx = 0.f;       // per-lane running max/sum for q = qg

  int nkv = qb + 1;                  // causal
  STAGE(0, (nkv - 1) * 64);          // diagonal tile first
  __syncthreads();
  int buf = 0;

  auto fa_step = [&](int kb, bool diag) {
    int ks = kb * 64;
    if (kb > 0) STAGE(buf ^ 1, ks - 64);   // prefetch (descending) under compute
    // ---- S^T = K Q^T : lane -> q=qg, k = ks + j*16 + g*4 + r ----
    f32x4 s[4] = {};
    __builtin_amdgcn_s_setprio(1);
#pragma unroll
    for (int j = 0; j < 4; ++j) {
      int row = j * 16 + ln, sw = (row & 7) << 3;
      bf16x8 kf0 = *(const bf16x8*)&Ks[buf][row * DKc + ((g * 8) ^ sw)];
      bf16x8 kf1 = *(const bf16x8*)&Ks[buf][row * DKc + ((32 + g * 8) ^ sw)];
      s[j] = mfma16(kf0, qf0, s[j]);
      s[j] = mfma16(kf1, qf1, s[j]);
    }
    __builtin_amdgcn_s_setprio(0);
    // ---- bias + (diag-only) mask; register-local max ----
    float vv[4][4];
    float mloc = -1e30f;
#pragma unroll
    for (int j = 0; j < 4; ++j)
#pragma unroll
      for (int r = 0; r < 4; ++r) {
        float t = s[j][r] + vb[j][r];
        if (diag) t = (j * 16 + g * 4 + r > wv16ln) ? -1e30f : t;
        vv[j][r] = t;
        mloc = fmaxf(mloc, t);
      }
    mloc = fmaxf(mloc, __shfl_xor(mloc, 16, 64));
    mloc = fmaxf(mloc, __shfl_xor(mloc, 32, 64));
    float cterm = slope2 * (float)(ks - qg);   // true score = vv + cterm
    float mc = mloc + cterm;
    if (__any(mc > Mx)) {                      // rescale only when max grows (rare)
      float newM = fmaxf(Mx, mc);
      float sc = __builtin_amdgcn_exp2f(Mx - newM);
      Mx = newM;
      Lx *= sc;
      float scb[4];
#pragma unroll
      for (int r = 0; r < 4; ++r) scb[r] = __shfl(sc, g * 4 + r, 64);
#pragma unroll
      for (int nd = 0; nd < 4; ++nd)
#pragma unroll
        for (int r = 0; r < 4; ++r) accO[nd][r] *= scb[r];
    }
    float dsub = Mx - cterm;
    float rs = 0.f;
#pragma unroll
    for (int j = 0; j < 4; ++j)
#pragma unroll
      for (int r = 0; r < 4; ++r) {
        float p = __builtin_amdgcn_exp2f(vv[j][r] - dsub);
        vv[j][r] = p;
        rs += p;
      }
    Lx += rs;                          // cross-g reduce deferred to epilogue
    // ---- P -> LDS: lane's 4 consecutive-k values per j, packed bf16 ----
    char* Prow = (char*)&P_lds[wave][ln][0];
    int psw = (ln & 7) << 4;
#pragma unroll
    for (int j = 0; j < 4; ++j) {
      u32x2 w;
      w.x = cvt_pk_bf16(vv[j][0], vv[j][1]);
      w.y = cvt_pk_bf16(vv[j][2], vv[j][3]);
      *(u32x2*)(Prow + ((j * 32 + g * 8) ^ psw)) = w;
    }
    // ---- O += P V ----
    __builtin_amdgcn_s_setprio(1);
#pragma unroll
    for (int kk = 0; kk < 2; ++kk) {
      bf16x8 pa = *(const bf16x8*)(Prow + ((kk * 64 + g * 16) ^ psw));
#pragma unroll
      for (int nd = 0; nd < 4; ++nd) {
        int d = nd * 16 + ln, o = kk * 32 + g * 8;
        bf16x8 vf = *(const bf16x8*)&Vs[buf][d * DKc + (o ^ ((d & 7) << 3))];
        accO[nd] = mfma16(pa, vf, accO[nd]);
      }
    }
    __builtin_amdgcn_s_setprio(0);
    __syncthreads();                   // next tile staged; buf free
    buf ^= 1;
  };

  fa_step(nkv - 1, true);              // diagonal (masked) tile first
  for (int kb = nkv - 2; kb >= 0; --kb) fa_step(kb, false);

  // ---- epilogue: finish L reduce, O /= L, write [B,T,D] bf16 ----
  float Lf = Lx + __shfl_xor(Lx, 16, 64);
  Lf = Lf + __shfl_xor(Lf, 32, 64);
  float linv[4];
#pragma unroll
  for (int r = 0; r < 4; ++r) linv[r] = 1.0f / __shfl(Lf, g * 4 + r, 64);
#pragma unroll
  for (int nd = 0; nd < 4; ++nd)
#pragma unroll
    for (int r = 0; r < 4; ++r) {
      int t = qb * 64 + wave * 16 + g * 4 + r;
      int dcol = h * 64 + nd * 16 + ln;
      O[((size_t)(b * Tc + t)) * Dc + dcol] = f2bf(accO[nd][r] * linv[r]);
    }
#undef STAGE
}

// -----------------------------------------------------------------------------
extern "C" void kernel_launch(void* const* d_in, const int* in_sizes, int n_in,
                              void* d_out, int out_size, void* d_ws, size_t ws_size,
                              hipStream_t stream) {
  const float* q  = (const float*)d_in[0];
  const float* k  = (const float*)d_in[1];
  const float* v  = (const float*)d_in[2];
  // d_in[3] = alibi_bias [H,T,T] — intentionally unused (computed on the fly)
  const float* wq = (const float*)d_in[4];
  const float* wk = (const float*)d_in[5];
  const float* wv = (const float*)d_in[6];
  const float* wo = (const float*)d_in[7];
  const float* bo = (const float*)d_in[8];

  char* ws = (char*)d_ws;
  const size_t MB = 1024 * 1024;
  u16* Xq = (u16*)(ws + 0 * MB);    // [4096,1024] bf16
  u16* Xk = (u16*)(ws + 8 * MB);
  u16* Xv = (u16*)(ws + 16 * MB);
  u16* Wq = (u16*)(ws + 24 * MB);   // [1024,1024] bf16
  u16* Wk = (u16*)(ws + 26 * MB);
  u16* Wv = (u16*)(ws + 28 * MB);
  u16* Wo = (u16*)(ws + 30 * MB);
  u16* Qh = (u16*)(ws + 32 * MB);   // [B,H,T,DK] bf16
  u16* Kh = (u16*)(ws + 40 * MB);   // [B,H,T,DK]
  u16* VT = (u16*)(ws + 48 * MB);   // [B,H,DK,T]
  u16* Ob = (u16*)(ws + 56 * MB);   // [B,T,D]
  float* out = (float*)d_out;

  // f32 -> bf16 (single dispatch: X's + W's)
  conv_kernel<<<dim3(4096 + 1024, 1, 4), 256, 0, stream>>>(q, k, v, wq, wk, wv, wo,
                                                           Xq, Xk, Xv, Wq, Wk, Wv, Wo);
  // fused Q/K/V projections (one dispatch, 768 blocks = 3 blocks/CU)
  gemm_proj<<<dim3(32, 8, 3), 256, 0, stream>>>(Xq, Xk, Xv, Wq, Wk, Wv, Qh, Kh, VT);
  // attention
  flash_attn<<<dim3(Tc / 64, Bc * Hc), 256, 0, stream>>>(Qh, Kh, VT, Ob);
  // output projection + bias -> f32 d_out (512 blocks = 2/CU)
  gemm_out<<<dim3(64, 8), 256, 0, stream>>>(Ob, Wo, out, bo);
}

// Round 6
// 127.821 us; speedup vs baseline: 2.6377x; 1.2053x over previous
//
#include <hip/hip_runtime.h>
#include <hip/hip_bf16.h>
#include <stdint.h>

// Problem constants (B=2, T=2048, D=1024, H=16, DK=64)
#define Bc   2
#define Tc   2048
#define Dc   1024
#define Hc   16
#define DKc  64
#define BTc  4096
#define LOG2E 1.44269504088896f

typedef unsigned short u16;
typedef unsigned int u32;
typedef __attribute__((ext_vector_type(8))) short bf16x8;
typedef __attribute__((ext_vector_type(4))) float f32x4;
typedef __attribute__((ext_vector_type(2))) u32 u32x2;

static __device__ __forceinline__ u16 f2bf(float f) {
  union { float f; unsigned u; } v; v.f = f;
  unsigned r = v.u + 0x7fffu + ((v.u >> 16) & 1u);   // RNE
  return (u16)(r >> 16);
}

static __device__ __forceinline__ u32 cvt_pk_bf16(float lo, float hi) {
  u32 r;
  asm volatile("v_cvt_pk_bf16_f32 %0, %1, %2" : "=v"(r) : "v"(lo), "v"(hi));
  return r;
}

static __device__ __forceinline__ f32x4 mfma16(bf16x8 a, bf16x8 b, f32x4 c) {
  return __builtin_amdgcn_mfma_f32_16x16x32_bf16(a, b, c, 0, 0, 0);
}

// ------------- f32 -> bf16 conversion: one dispatch for all 7 tensors --------
__global__ void conv_kernel(const float* __restrict__ q, const float* __restrict__ k,
                            const float* __restrict__ v, const float* __restrict__ wq,
                            const float* __restrict__ wk, const float* __restrict__ wv,
                            const float* __restrict__ wo,
                            u16* __restrict__ Xq, u16* __restrict__ Xk, u16* __restrict__ Xv,
                            u16* __restrict__ Wq, u16* __restrict__ Wk, u16* __restrict__ Wv,
                            u16* __restrict__ Wo) {
  int z = blockIdx.z, bx = blockIdx.x;
  const float* src; u16* dst; int i;
  if (bx < 4096) {
    if (z == 3) return;
    src = z == 0 ? q : z == 1 ? k : v;
    dst = z == 0 ? Xq : z == 1 ? Xk : Xv;
    i = bx * 256 + threadIdx.x;
  } else {
    src = z == 0 ? wq : z == 1 ? wk : z == 2 ? wv : wo;
    dst = z == 0 ? Wq : z == 1 ? Wk : z == 2 ? Wv : Wo;
    i = (bx - 4096) * 256 + threadIdx.x;
  }
  float4 f = ((const float4*)src)[i];
  ushort4 r; r.x = f2bf(f.x); r.y = f2bf(f.y); r.z = f2bf(f.z); r.w = f2bf(f.w);
  ((ushort4*)dst)[i] = r;
}

#define AS1 const __attribute__((address_space(1))) void*
#define AS3 __attribute__((address_space(3))) void*

// ---------- fused Q/K/V projection: grid.z picks tensor (3 blocks/CU) --------
__global__ __launch_bounds__(256) void gemm_proj(const u16* __restrict__ Xq, const u16* __restrict__ Xk,
                                                 const u16* __restrict__ Xv, const u16* __restrict__ Wq,
                                                 const u16* __restrict__ Wk, const u16* __restrict__ Wv,
                                                 u16* __restrict__ Qh, u16* __restrict__ Kh,
                                                 u16* __restrict__ VTo) {
  __shared__ u16 As[128 * 32];
  __shared__ u16 Bs[128 * 32];
  int z = blockIdx.z;
  const u16* A = z == 0 ? Xq : z == 1 ? Xk : Xv;
  const u16* W = z == 0 ? Wq : z == 1 ? Wk : Wv;
  u16* outp    = z == 0 ? Qh : z == 1 ? Kh : VTo;
  float scale = (z == 0) ? 0.125f * LOG2E : 1.0f;   // fold 1/sqrt(DK)*log2e into Q
  int tid = threadIdx.x;
  int lane = tid & 63, wave = tid >> 6;
  int ln = lane & 15, g = lane >> 4;
  int m0 = blockIdx.x * 128, n0 = blockIdx.y * 128;
  int wm = (wave >> 1) * 64, wn = (wave & 1) * 64;
  f32x4 acc[4][4] = {};
  int c0 = tid, c1 = tid + 256;
  const u16* gA0 = A + (size_t)(m0 + (c0 >> 2)) * 1024 + (c0 & 3) * 8;
  const u16* gA1 = A + (size_t)(m0 + (c1 >> 2)) * 1024 + (c1 & 3) * 8;
  const u16* gW0 = W + (size_t)(n0 + (c0 >> 2)) * 1024 + (c0 & 3) * 8;
  const u16* gW1 = W + (size_t)(n0 + (c1 >> 2)) * 1024 + (c1 & 3) * 8;
  for (int k0 = 0; k0 < 1024; k0 += 32) {
    __builtin_amdgcn_global_load_lds((AS1)(gA0 + k0), (AS3)(As + c0 * 8), 16, 0, 0);
    __builtin_amdgcn_global_load_lds((AS1)(gA1 + k0), (AS3)(As + c1 * 8), 16, 0, 0);
    __builtin_amdgcn_global_load_lds((AS1)(gW0 + k0), (AS3)(Bs + c0 * 8), 16, 0, 0);
    __builtin_amdgcn_global_load_lds((AS1)(gW1 + k0), (AS3)(Bs + c1 * 8), 16, 0, 0);
    __syncthreads();
    bf16x8 af[4], bfr[4];
#pragma unroll
    for (int mi = 0; mi < 4; ++mi) af[mi]  = *(const bf16x8*)&As[(wm + mi * 16 + ln) * 32 + g * 8];
#pragma unroll
    for (int ni = 0; ni < 4; ++ni) bfr[ni] = *(const bf16x8*)&Bs[(wn + ni * 16 + ln) * 32 + g * 8];
#pragma unroll
    for (int mi = 0; mi < 4; ++mi)
#pragma unroll
      for (int ni = 0; ni < 4; ++ni)
        acc[mi][ni] = mfma16(af[mi], bfr[ni], acc[mi][ni]);
    __syncthreads();
  }
  if (z == 2) {
    // V^T [B,H,DK,T]: r-consecutive values are t-adjacent -> pack 4 into 8B
#pragma unroll
    for (int mi = 0; mi < 4; ++mi)
#pragma unroll
      for (int ni = 0; ni < 4; ++ni) {
        int t0 = m0 + wm + mi * 16 + g * 4;
        int gn = n0 + wn + ni * 16 + ln;
        size_t bhead = ((size_t)(t0 >> 11)) * Hc + (gn >> 6);
        ushort4 pk;
        pk.x = f2bf(acc[mi][ni][0]); pk.y = f2bf(acc[mi][ni][1]);
        pk.z = f2bf(acc[mi][ni][2]); pk.w = f2bf(acc[mi][ni][3]);
        *(ushort4*)&outp[(bhead * DKc + (gn & 63)) * Tc + (t0 & 2047)] = pk;
      }
  } else {
#pragma unroll
    for (int mi = 0; mi < 4; ++mi)
#pragma unroll
      for (int ni = 0; ni < 4; ++ni)
#pragma unroll
        for (int r = 0; r < 4; ++r) {
          int gm = m0 + wm + mi * 16 + g * 4 + r;
          int gn = n0 + wn + ni * 16 + ln;
          size_t bhead = ((size_t)(gm >> 11)) * Hc + (gn >> 6);
          outp[(bhead * Tc + (gm & 2047)) * DKc + (gn & 63)] = f2bf(acc[mi][ni][r] * scale);
        }
  }
}

// ---------- output projection + bias -> f32 (BM=64: 512 blocks, 2/CU) --------
__global__ __launch_bounds__(256) void gemm_out(const u16* __restrict__ Ain, const u16* __restrict__ W,
                                                float* __restrict__ of, const float* __restrict__ bias) {
  __shared__ u16 As[64 * 32];
  __shared__ u16 Bs[128 * 32];
  int tid = threadIdx.x;
  int lane = tid & 63, wave = tid >> 6;
  int ln = lane & 15, g = lane >> 4;
  int m0 = blockIdx.x * 64, n0 = blockIdx.y * 128;
  int wm = (wave >> 1) * 32, wn = (wave & 1) * 64;
  f32x4 acc[2][4] = {};
  int ca = tid, cb0 = tid, cb1 = tid + 256;
  const u16* gA  = Ain + (size_t)(m0 + (ca  >> 2)) * 1024 + (ca  & 3) * 8;
  const u16* gW0 = W   + (size_t)(n0 + (cb0 >> 2)) * 1024 + (cb0 & 3) * 8;
  const u16* gW1 = W   + (size_t)(n0 + (cb1 >> 2)) * 1024 + (cb1 & 3) * 8;
  for (int k0 = 0; k0 < 1024; k0 += 32) {
    __builtin_amdgcn_global_load_lds((AS1)(gA  + k0), (AS3)(As + ca  * 8), 16, 0, 0);
    __builtin_amdgcn_global_load_lds((AS1)(gW0 + k0), (AS3)(Bs + cb0 * 8), 16, 0, 0);
    __builtin_amdgcn_global_load_lds((AS1)(gW1 + k0), (AS3)(Bs + cb1 * 8), 16, 0, 0);
    __syncthreads();
    bf16x8 af[2], bfr[4];
#pragma unroll
    for (int mi = 0; mi < 2; ++mi) af[mi]  = *(const bf16x8*)&As[(wm + mi * 16 + ln) * 32 + g * 8];
#pragma unroll
    for (int ni = 0; ni < 4; ++ni) bfr[ni] = *(const bf16x8*)&Bs[(wn + ni * 16 + ln) * 32 + g * 8];
#pragma unroll
    for (int mi = 0; mi < 2; ++mi)
#pragma unroll
      for (int ni = 0; ni < 4; ++ni)
        acc[mi][ni] = mfma16(af[mi], bfr[ni], acc[mi][ni]);
    __syncthreads();
  }
#pragma unroll
  for (int mi = 0; mi < 2; ++mi)
#pragma unroll
    for (int ni = 0; ni < 4; ++ni)
#pragma unroll
      for (int r = 0; r < 4; ++r) {
        int gm = m0 + wm + mi * 16 + g * 4 + r;
        int gn = n0 + wn + ni * 16 + ln;
        of[(size_t)gm * 1024 + gn] = acc[mi][ni][r] + bias[gn];
      }
}

// -------- Flash attention, paired q-tiles for perfect load balance ----------
// grid (16, 32): block owns q-tiles qhi=16+pid and qlo=15-pid -> every block
// does exactly 33 tile-computations and qhi+1 stagings. kv descends from qhi
// so each tile sees its own diagonal first (defer-max valid for both).
__global__ __launch_bounds__(256, 2) void flash_attn(const u16* __restrict__ Qh,
                                                     const u16* __restrict__ Kh,
                                                     const u16* __restrict__ VT,
                                                     u16* __restrict__ O) {
  __shared__ u16 Ks[2][64 * 64];     // [kv_row][dk], XOR-swizzled (byte^=(row&7)<<4)
  __shared__ u16 Vs[2][64 * 64];     // [dk][t_off], XOR-swizzled
  __shared__ u16 P_lds[8][16][64];   // [tile*4+wave][q][k], XOR-swizzled
  int pid = blockIdx.x, bh = blockIdx.y;
  int qhi = 16 + pid, qlo = 15 - pid;
  int b = bh >> 4, h = bh & (Hc - 1);
  int tid = threadIdx.x, wave = tid >> 6, lane = tid & 63;
  int ln = lane & 15, g = lane >> 4;
  float slope2 = exp2f(-0.5f * (float)(h + 1)) * LOG2E;   // slope_h * log2(e)

  const u16* gK = Kh + (size_t)bh * Tc * DKc;
  const u16* gV = VT + (size_t)bh * DKc * Tc;
  // staging: pre-swizzled global source + linear LDS dest (rule #21)
  int c0 = tid, c1 = tid + 256;
  int r0 = c0 >> 3, r1 = c1 >> 3;
  int e0 = ((c0 & 7) << 3) ^ ((r0 & 7) << 3);
  int e1 = ((c1 & 7) << 3) ^ ((r1 & 7) << 3);
  size_t kO0 = (size_t)r0 * DKc + e0, kO1 = (size_t)r1 * DKc + e1;
  size_t vO0 = (size_t)r0 * Tc + e0, vO1 = (size_t)r1 * Tc + e1;

#define STAGE(bufi, ks_) do {                                                                  \
    __builtin_amdgcn_global_load_lds((AS1)(gK + (size_t)(ks_) * DKc + kO0),                    \
                                     (AS3)(&Ks[bufi][c0 * 8]), 16, 0, 0);                      \
    __builtin_amdgcn_global_load_lds((AS1)(gK + (size_t)(ks_) * DKc + kO1),                    \
                                     (AS3)(&Ks[bufi][c1 * 8]), 16, 0, 0);                      \
    __builtin_amdgcn_global_load_lds((AS1)(gV + (size_t)(ks_) + vO0),                          \
                                     (AS3)(&Vs[bufi][c0 * 8]), 16, 0, 0);                      \
    __builtin_amdgcn_global_load_lds((AS1)(gV + (size_t)(ks_) + vO1),                          \
                                     (AS3)(&Vs[bufi][c1 * 8]), 16, 0, 0);                      \
  } while (0)

  int qlocal = wave * 16 + ln;       // lane's q-row within a 64-row tile
  int qgH = qhi * 64 + qlocal, qgL = qlo * 64 + qlocal;
  const u16* QpH = Qh + ((size_t)bh * Tc + qgH) * DKc;
  const u16* QpL = Qh + ((size_t)bh * Tc + qgL) * DKc;
  bf16x8 qfH0 = *(const bf16x8*)&QpH[g * 8];
  bf16x8 qfH1 = *(const bf16x8*)&QpH[32 + g * 8];
  bf16x8 qfL0 = *(const bf16x8*)&QpL[g * 8];
  bf16x8 qfL1 = *(const bf16x8*)&QpL[32 + g * 8];

  // per-lane ALiBi offsets for the k's this lane owns: k_local = j*16+g*4+r
  float vb[4][4];
#pragma unroll
  for (int j = 0; j < 4; ++j)
#pragma unroll
    for (int r = 0; r < 4; ++r)
      vb[j][r] = slope2 * (float)(j * 16 + g * 4 + r);

  f32x4 accH[4] = {}, accL[4] = {};
  float MH = -1e30f, LH = 0.f, ML = -1e30f, LL = 0.f;

  // one tile-step: QK^T (swapped), softmax (defer-max), PV accumulate
  auto tile_step = [&](int buf, int ks, bool diag, bf16x8 qf0, bf16x8 qf1,
                       int qg, float& Mx, float& Lx, f32x4* accO, int pslot) {
    f32x4 s[4] = {};
    __builtin_amdgcn_s_setprio(1);
#pragma unroll
    for (int j = 0; j < 4; ++j) {
      int row = j * 16 + ln, sw = (row & 7) << 3;
      bf16x8 kf0 = *(const bf16x8*)&Ks[buf][row * DKc + ((g * 8) ^ sw)];
      bf16x8 kf1 = *(const bf16x8*)&Ks[buf][row * DKc + ((32 + g * 8) ^ sw)];
      s[j] = mfma16(kf0, qf0, s[j]);
      s[j] = mfma16(kf1, qf1, s[j]);
    }
    __builtin_amdgcn_s_setprio(0);
    float vv[4][4];
    float mloc = -1e30f;
#pragma unroll
    for (int j = 0; j < 4; ++j)
#pragma unroll
      for (int r = 0; r < 4; ++r) {
        float t = s[j][r] + vb[j][r];
        if (diag) t = (j * 16 + g * 4 + r > qlocal) ? -1e30f : t;
        vv[j][r] = t;
        mloc = fmaxf(mloc, t);
      }
    mloc = fmaxf(mloc, __shfl_xor(mloc, 16, 64));
    mloc = fmaxf(mloc, __shfl_xor(mloc, 32, 64));
    float cterm = slope2 * (float)(ks - qg);   // true score = vv + cterm
    float mc = mloc + cterm;
    if (__any(mc > Mx)) {                      // rescale only when max grows (rare)
      float newM = fmaxf(Mx, mc);
      float sc = __builtin_amdgcn_exp2f(Mx - newM);
      Mx = newM;
      Lx *= sc;
      float scb[4];
#pragma unroll
      for (int r = 0; r < 4; ++r) scb[r] = __shfl(sc, g * 4 + r, 64);
#pragma unroll
      for (int nd = 0; nd < 4; ++nd)
#pragma unroll
        for (int r = 0; r < 4; ++r) accO[nd][r] *= scb[r];
    }
    float dsub = Mx - cterm;
    float rs = 0.f;
#pragma unroll
    for (int j = 0; j < 4; ++j)
#pragma unroll
      for (int r = 0; r < 4; ++r) {
        float p = __builtin_amdgcn_exp2f(vv[j][r] - dsub);
        vv[j][r] = p;
        rs += p;
      }
    Lx += rs;                          // cross-g reduce deferred to epilogue
    char* Prow = (char*)&P_lds[pslot][ln][0];
    int psw = (ln & 7) << 4;
#pragma unroll
    for (int j = 0; j < 4; ++j) {
      u32x2 w;
      w.x = cvt_pk_bf16(vv[j][0], vv[j][1]);
      w.y = cvt_pk_bf16(vv[j][2], vv[j][3]);
      *(u32x2*)(Prow + ((j * 32 + g * 8) ^ psw)) = w;
    }
    __builtin_amdgcn_s_setprio(1);
#pragma unroll
    for (int kk = 0; kk < 2; ++kk) {
      bf16x8 pa = *(const bf16x8*)(Prow + ((kk * 64 + g * 16) ^ psw));
#pragma unroll
      for (int nd = 0; nd < 4; ++nd) {
        int d = nd * 16 + ln, o = kk * 32 + g * 8;
        bf16x8 vf = *(const bf16x8*)&Vs[buf][d * DKc + (o ^ ((d & 7) << 3))];
        accO[nd] = mfma16(pa, vf, accO[nd]);
      }
    }
    __builtin_amdgcn_s_setprio(0);
  };

  STAGE(0, qhi * 64);                // hi diagonal tile first
  __syncthreads();
  int buf = 0;
  for (int kb = qhi; kb >= 0; --kb) {
    int ks = kb * 64;
    if (kb > 0) STAGE(buf ^ 1, ks - 64);   // prefetch (descending) under compute
    tile_step(buf, ks, kb == qhi, qfH0, qfH1, qgH, MH, LH, accH, wave);
    if (kb <= qlo)
      tile_step(buf, ks, kb == qlo, qfL0, qfL1, qgL, ML, LL, accL, wave + 4);
    __syncthreads();                 // next tile staged; buf free
    buf ^= 1;
  }

  // ---- epilogue: finish L reduce, O /= L, write [B,T,D] bf16 (both tiles) ----
#pragma unroll
  for (int tile = 0; tile < 2; ++tile) {
    float Lx = tile ? LL : LH;
    f32x4* accO = tile ? accL : accH;
    int qb = tile ? qlo : qhi;
    float Lf = Lx + __shfl_xor(Lx, 16, 64);
    Lf = Lf + __shfl_xor(Lf, 32, 64);
    float linv[4];
#pragma unroll
    for (int r = 0; r < 4; ++r) linv[r] = 1.0f / __shfl(Lf, g * 4 + r, 64);
#pragma unroll
    for (int nd = 0; nd < 4; ++nd)
#pragma unroll
      for (int r = 0; r < 4; ++r) {
        int t = qb * 64 + wave * 16 + g * 4 + r;
        int dcol = h * 64 + nd * 16 + ln;
        O[((size_t)(b * Tc + t)) * Dc + dcol] = f2bf(accO[nd][r] * linv[r]);
      }
  }
#undef STAGE
}

// -----------------------------------------------------------------------------
extern "C" void kernel_launch(void* const* d_in, const int* in_sizes, int n_in,
                              void* d_out, int out_size, void* d_ws, size_t ws_size,
                              hipStream_t stream) {
  const float* q  = (const float*)d_in[0];
  const float* k  = (const float*)d_in[1];
  const float* v  = (const float*)d_in[2];
  // d_in[3] = alibi_bias [H,T,T] — intentionally unused (computed on the fly)
  const float* wq = (const float*)d_in[4];
  const float* wk = (const float*)d_in[5];
  const float* wv = (const float*)d_in[6];
  const float* wo = (const float*)d_in[7];
  const float* bo = (const float*)d_in[8];

  char* ws = (char*)d_ws;
  const size_t MB = 1024 * 1024;
  u16* Xq = (u16*)(ws + 0 * MB);    // [4096,1024] bf16
  u16* Xk = (u16*)(ws + 8 * MB);
  u16* Xv = (u16*)(ws + 16 * MB);
  u16* Wq = (u16*)(ws + 24 * MB);   // [1024,1024] bf16
  u16* Wk = (u16*)(ws + 26 * MB);
  u16* Wv = (u16*)(ws + 28 * MB);
  u16* Wo = (u16*)(ws + 30 * MB);
  u16* Qh = (u16*)(ws + 32 * MB);   // [B,H,T,DK] bf16
  u16* Kh = (u16*)(ws + 40 * MB);   // [B,H,T,DK]
  u16* VT = (u16*)(ws + 48 * MB);   // [B,H,DK,T]
  u16* Ob = (u16*)(ws + 56 * MB);   // [B,T,D]
  float* out = (float*)d_out;

  // f32 -> bf16 (single dispatch: X's + W's)
  conv_kernel<<<dim3(4096 + 1024, 1, 4), 256, 0, stream>>>(q, k, v, wq, wk, wv, wo,
                                                           Xq, Xk, Xv, Wq, Wk, Wv, Wo);
  // fused Q/K/V projections (one dispatch, 768 blocks = 3 blocks/CU)
  gemm_proj<<<dim3(32, 8, 3), 256, 0, stream>>>(Xq, Xk, Xv, Wq, Wk, Wv, Qh, Kh, VT);
  // attention (paired q-tiles: 512 blocks, perfectly balanced)
  flash_attn<<<dim3(16, Bc * Hc), 256, 0, stream>>>(Qh, Kh, VT, Ob);
  // output projection + bias -> f32 d_out (512 blocks = 2/CU)
  gemm_out<<<dim3(64, 8), 256, 0, stream>>>(Ob, Wo, out, bo);
}